// Round 15
// baseline (1811.493 us; speedup 1.0000x reference)
//
#include <hip/hip_runtime.h>
#include <cstdint>
#include <cstddef>

#define BATCH 8
#define SEQ   256
#define HID   1024
#define GATES 4096   // 4*HID
#define VOC   32000

typedef __attribute__((ext_vector_type(8))) short bf16x8;
typedef __attribute__((ext_vector_type(4))) float f32x4;

// ---------- helpers ----------
__device__ __forceinline__ float sigf(float x){ return 1.0f/(1.0f + __expf(-x)); }
__device__ __forceinline__ float tanhf_(float x){ return 1.0f - 2.0f/(__expf(2.0f*x) + 1.0f); }

__device__ __forceinline__ unsigned short f2bf(float x){
  union { float f; unsigned u; } v; v.f = x;
  unsigned r = v.u + 0x7fffu + ((v.u >> 16) & 1u);
  return (unsigned short)(r >> 16);
}
__device__ __forceinline__ float bf2f(unsigned short h){
  union { float f; unsigned u; } v; v.u = ((unsigned)h) << 16; return v.f;
}

// ---------- k_pre: heterogeneous pre-pass ----------
// blocks y<8: G0 = emb[tok]@Wx0 + (bx0+bh0)  (split-bf16 MFMA, R8-validated body)
// blocks y>=8 (224 blocks): init flags/hbu + Wd->bf16 conversion (if wpre)
__global__ __launch_bounds__(256) void k_pre(
    const float* __restrict__ W,     // Wx0 [1024][4096]
    const float* __restrict__ b1,    // bx0
    const float* __restrict__ b2,    // bh0
    const int*   __restrict__ tokens,
    const float* __restrict__ emb,
    float* __restrict__ C,           // G0
    unsigned* __restrict__ flags,
    unsigned* __restrict__ hbu,
    const float* __restrict__ Wd,
    unsigned short* __restrict__ WH,
    int wpre)
{
  __shared__ unsigned short AsH[16*1024], AsL[16*1024];
  __shared__ unsigned short BsH[8*1024],  BsL[8*1024];
  int tid = threadIdx.x;

  if (blockIdx.y >= 8){
    // ---- service branch: init + wconv ----
    int sid = (blockIdx.y - 8)*32 + blockIdx.x;   // 0..223
    int gtid = sid*256 + tid, nt = 224*256;
    for (int i = gtid; i < 256*16; i += nt) flags[i] = 0u;
    for (int i = gtid; i < 16384; i += nt) hbu[i] = 0u;
    if (wpre){
      const int total4 = (HID*VOC) >> 2;
      for (int i = gtid; i < total4; i += nt){
        float4 v = *(const float4*)(Wd + (size_t)i*4);
        uint2 o;
        o.x = ((unsigned)f2bf(v.x)) | (((unsigned)f2bf(v.y)) << 16);
        o.y = ((unsigned)f2bf(v.z)) | (((unsigned)f2bf(v.w)) << 16);
        *(uint2*)&WH[(size_t)i*4] = o;
      }
    }
    return;
  }

  // ---- G0 MFMA branch ----
  const int N = GATES;
  int m0 = blockIdx.y*256, n0 = blockIdx.x*128;
  int w = tid >> 6, l = tid & 63;
  int lrow = l & 15, kg = l >> 4;

  f32x4 acc[4][8];
  #pragma unroll
  for (int i=0;i<4;i++){
    #pragma unroll
    for (int j=0;j<8;j++) acc[i][j] = (f32x4){0.f,0.f,0.f,0.f};
  }

  int rA  = tid >> 3, fq = tid & 7;

  const float* arow[8];
  #pragma unroll
  for (int i=0;i<8;i++){
    int gm = m0 + rA + 32*i;
    arow[i] = emb + (size_t)tokens[(gm&7)*SEQ + (gm>>3)]*1024;
  }

  for (int kt=0; kt<32; ++kt){
    int k0 = kt*32;
    float4 av[8];
    #pragma unroll
    for (int i=0;i<8;i++)
      av[i] = *(const float4*)(arow[i] + k0 + fq*4);
    float4 wv[4];
    #pragma unroll
    for (int i=0;i<4;i++)
      wv[i] = *(const float4*)(W + (size_t)(k0 + rA)*N + n0 + fq*4 + 32*i);
    __syncthreads();
    #pragma unroll
    for (int i=0;i<8;i++){
      int r = rA + 32*i;
      int base = (r >> 4)*1024 + ((fq >> 1)*16 + (r & 15))*8 + (fq & 1)*4;
      float xs[4] = {av[i].x, av[i].y, av[i].z, av[i].w};
      unsigned long long ph = 0ull, pl = 0ull;
      #pragma unroll
      for (int c=0;c<4;c++){
        unsigned short h = f2bf(xs[c]);
        unsigned short lo = f2bf(xs[c] - bf2f(h));
        ph |= ((unsigned long long)h) << (16*c);
        pl |= ((unsigned long long)lo) << (16*c);
      }
      *(unsigned long long*)&AsH[base] = ph;
      *(unsigned long long*)&AsL[base] = pl;
    }
    #pragma unroll
    for (int i=0;i<4;i++){
      float xs[4] = {wv[i].x, wv[i].y, wv[i].z, wv[i].w};
      #pragma unroll
      for (int c=0;c<4;c++){
        int col = fq*4 + 32*i + c;
        int idx = (col >> 4)*1024 + ((rA >> 3)*16 + (col & 15))*8 + (rA & 7);
        unsigned short h = f2bf(xs[c]);
        BsH[idx] = h;
        BsL[idx] = f2bf(xs[c] - bf2f(h));
      }
    }
    __syncthreads();
    bf16x8 ah[4], al[4];
    #pragma unroll
    for (int i=0;i<4;i++){
      int fi = w*4 + i;
      ah[i] = *(const bf16x8*)&AsH[fi*1024 + l*8];
      al[i] = *(const bf16x8*)&AsL[fi*1024 + l*8];
    }
    #pragma unroll
    for (int jh=0;jh<2;jh++){
      bf16x8 bh_[4], bl_[4];
      #pragma unroll
      for (int j=0;j<4;j++){
        bh_[j] = *(const bf16x8*)&BsH[(jh*4+j)*1024 + l*8];
        bl_[j] = *(const bf16x8*)&BsL[(jh*4+j)*1024 + l*8];
      }
      #pragma unroll
      for (int i=0;i<4;i++){
        #pragma unroll
        for (int j=0;j<4;j++){
          f32x4 a = acc[i][jh*4+j];
          a = __builtin_amdgcn_mfma_f32_16x16x32_bf16(ah[i], bh_[j], a, 0,0,0);
          a = __builtin_amdgcn_mfma_f32_16x16x32_bf16(ah[i], bl_[j], a, 0,0,0);
          a = __builtin_amdgcn_mfma_f32_16x16x32_bf16(al[i], bh_[j], a, 0,0,0);
          acc[i][jh*4+j] = a;
        }
      }
    }
    __syncthreads();
  }

  int mbase = m0 + w*64 + kg*4;
  #pragma unroll
  for (int jj=0;jj<8;jj++){
    int gn = n0 + jj*16 + lrow;
    float bias = b1[gn] + b2[gn];
    #pragma unroll
    for (int i=0;i<4;i++){
      #pragma unroll
      for (int r=0;r<4;r++){
        int m = mbase + i*16 + r;
        C[(size_t)m*N + gn] = acc[i][jj][r] + bias;
      }
    }
  }
}

// ---------- k_proj1: 2-pass projection, single-bf16 W, 80KB LDS, prefetch (R14-proven) ----------
__global__ __launch_bounds__(256,2) void k_proj1(
    const unsigned short* __restrict__ AH,
    const unsigned short* __restrict__ AL,
    const unsigned short* __restrict__ WH,
    const float* __restrict__ bd,
    float* __restrict__ C)
{
  __shared__ unsigned short AsH[16*1024], AsL[16*1024];
  __shared__ unsigned short BsH[8*1024];
  int tid = threadIdx.x;
  int m0 = blockIdx.y*256, n0 = blockIdx.x*128;
  int w = tid >> 6, l = tid & 63;
  int lrow = l & 15, kg = l >> 4;

  f32x4 acc[4][8];
  #pragma unroll
  for (int i=0;i<4;i++){
    #pragma unroll
    for (int j=0;j<8;j++) acc[i][j] = (f32x4){0.f,0.f,0.f,0.f};
  }

  int rA = tid >> 3, fq = tid & 7;

  uint2 avh[8], avl[8], wvh[4];
  #pragma unroll
  for (int i=0;i<8;i++){
    size_t off = (size_t)(m0 + rA + 32*i)*1024 + fq*4;
    avh[i] = *(const uint2*)&AH[off];
    avl[i] = *(const uint2*)&AL[off];
  }
  #pragma unroll
  for (int i=0;i<4;i++)
    wvh[i] = *(const uint2*)&WH[(size_t)rA*VOC + n0 + fq*4 + 32*i];

  for (int kt=0; kt<32; ++kt){
    __syncthreads();
    #pragma unroll
    for (int i=0;i<8;i++){
      int r = rA + 32*i;
      int base = (r >> 4)*1024 + ((fq >> 1)*16 + (r & 15))*8 + (fq & 1)*4;
      *(uint2*)&AsH[base] = avh[i];
      *(uint2*)&AsL[base] = avl[i];
    }
    #pragma unroll
    for (int i=0;i<4;i++){
      #pragma unroll
      for (int c=0;c<4;c++){
        int col = fq*4 + 32*i + c;
        int idx = (col >> 4)*1024 + ((rA >> 3)*16 + (col & 15))*8 + (rA & 7);
        BsH[idx] = ((const unsigned short*)&wvh[i])[c];
      }
    }
    __syncthreads();
    if (kt < 31){
      int k0 = (kt+1)*32;
      #pragma unroll
      for (int i=0;i<8;i++){
        size_t off = (size_t)(m0 + rA + 32*i)*1024 + k0 + fq*4;
        avh[i] = *(const uint2*)&AH[off];
        avl[i] = *(const uint2*)&AL[off];
      }
      #pragma unroll
      for (int i=0;i<4;i++)
        wvh[i] = *(const uint2*)&WH[(size_t)(k0 + rA)*VOC + n0 + fq*4 + 32*i];
    }
    bf16x8 ah[4], al[4];
    #pragma unroll
    for (int i=0;i<4;i++){
      int fi = w*4 + i;
      ah[i] = *(const bf16x8*)&AsH[fi*1024 + l*8];
      al[i] = *(const bf16x8*)&AsL[fi*1024 + l*8];
    }
    #pragma unroll
    for (int jh=0;jh<2;jh++){
      bf16x8 bh_[4];
      #pragma unroll
      for (int j=0;j<4;j++)
        bh_[j] = *(const bf16x8*)&BsH[(jh*4+j)*1024 + l*8];
      #pragma unroll
      for (int i=0;i<4;i++){
        #pragma unroll
        for (int j=0;j<4;j++){
          f32x4 a = acc[i][jh*4+j];
          a = __builtin_amdgcn_mfma_f32_16x16x32_bf16(ah[i], bh_[j], a, 0,0,0);
          a = __builtin_amdgcn_mfma_f32_16x16x32_bf16(al[i], bh_[j], a, 0,0,0);
          acc[i][jh*4+j] = a;
        }
      }
    }
  }
  __syncthreads();

  int mbase = m0 + w*64 + kg*4;
  #pragma unroll
  for (int jj=0;jj<8;jj++){
    int gn = n0 + jj*16 + lrow;
    float bias = bd[gn];
    #pragma unroll
    for (int i=0;i<4;i++){
      #pragma unroll
      for (int r=0;r<4;r++){
        int m = mbase + i*16 + r;
        size_t crow = (size_t)((m & 7)*SEQ + (m >> 3));
        C[crow*(size_t)VOC + gn] = acc[i][jj][r] + bias;
      }
    }
  }
}

// ---------- k_proj0: fallback (f32 W, 3-pass, R13-proven) ----------
__global__ __launch_bounds__(256) void k_proj0(
    const unsigned short* __restrict__ AH,
    const unsigned short* __restrict__ AL,
    const float* __restrict__ Wf,
    const float* __restrict__ bd,
    float* __restrict__ C)
{
  __shared__ unsigned short AsH[16*1024], AsL[16*1024];
  __shared__ unsigned short BsH[8*1024],  BsL[8*1024];
  int tid = threadIdx.x;
  int m0 = blockIdx.y*256, n0 = blockIdx.x*128;
  int w = tid >> 6, l = tid & 63;
  int lrow = l & 15, kg = l >> 4;

  f32x4 acc[4][8];
  #pragma unroll
  for (int i=0;i<4;i++){
    #pragma unroll
    for (int j=0;j<8;j++) acc[i][j] = (f32x4){0.f,0.f,0.f,0.f};
  }

  int rA = tid >> 3, fq = tid & 7;

  for (int kt=0; kt<32; ++kt){
    int k0 = kt*32;
    uint2 avh[8], avl[8];
    #pragma unroll
    for (int i=0;i<8;i++){
      size_t off = (size_t)(m0 + rA + 32*i)*1024 + k0 + fq*4;
      avh[i] = *(const uint2*)&AH[off];
      avl[i] = *(const uint2*)&AL[off];
    }
    float4 wvf[4];
    #pragma unroll
    for (int i=0;i<4;i++)
      wvf[i] = *(const float4*)(Wf + (size_t)(k0 + rA)*VOC + n0 + fq*4 + 32*i);
    __syncthreads();
    #pragma unroll
    for (int i=0;i<8;i++){
      int r = rA + 32*i;
      int base = (r >> 4)*1024 + ((fq >> 1)*16 + (r & 15))*8 + (fq & 1)*4;
      *(uint2*)&AsH[base] = avh[i];
      *(uint2*)&AsL[base] = avl[i];
    }
    #pragma unroll
    for (int i=0;i<4;i++){
      float xs[4] = {wvf[i].x, wvf[i].y, wvf[i].z, wvf[i].w};
      #pragma unroll
      for (int c=0;c<4;c++){
        int col = fq*4 + 32*i + c;
        int idx = (col >> 4)*1024 + ((rA >> 3)*16 + (col & 15))*8 + (rA & 7);
        unsigned short h = f2bf(xs[c]);
        BsH[idx] = h;
        BsL[idx] = f2bf(xs[c] - bf2f(h));
      }
    }
    __syncthreads();
    bf16x8 ah[4], al[4];
    #pragma unroll
    for (int i=0;i<4;i++){
      int fi = w*4 + i;
      ah[i] = *(const bf16x8*)&AsH[fi*1024 + l*8];
      al[i] = *(const bf16x8*)&AsL[fi*1024 + l*8];
    }
    #pragma unroll
    for (int jh=0;jh<2;jh++){
      bf16x8 bh_[4], bl_[4];
      #pragma unroll
      for (int j=0;j<4;j++){
        bh_[j] = *(const bf16x8*)&BsH[(jh*4+j)*1024 + l*8];
        bl_[j] = *(const bf16x8*)&BsL[(jh*4+j)*1024 + l*8];
      }
      #pragma unroll
      for (int i=0;i<4;i++){
        #pragma unroll
        for (int j=0;j<4;j++){
          f32x4 a = acc[i][jh*4+j];
          a = __builtin_amdgcn_mfma_f32_16x16x32_bf16(ah[i], bh_[j], a, 0,0,0);
          a = __builtin_amdgcn_mfma_f32_16x16x32_bf16(ah[i], bl_[j], a, 0,0,0);
          a = __builtin_amdgcn_mfma_f32_16x16x32_bf16(al[i], bh_[j], a, 0,0,0);
          acc[i][jh*4+j] = a;
        }
      }
    }
    __syncthreads();
  }

  int mbase = m0 + w*64 + kg*4;
  #pragma unroll
  for (int jj=0;jj<8;jj++){
    int gn = n0 + jj*16 + lrow;
    float bias = bd[gn];
    #pragma unroll
    for (int i=0;i<4;i++){
      #pragma unroll
      for (int r=0;r<4;r++){
        int m = mbase + i*16 + r;
        size_t crow = (size_t)((m & 7)*SEQ + (m >> 3));
        C[crow*(size_t)VOC + gn] = acc[i][jj][r] + bias;
      }
    }
  }
}

// ---------- fused 2-layer pipelined recurrence (R12-proven transport +
//            R15 scheduling: split stage issue/wait, Tops store off drain) ----------
__global__ __launch_bounds__(256) void k_rec2(
    const float* __restrict__ G,      // G0 [2048][4096], bias folded
    const float* __restrict__ Wh,     // [2][1024][4096]
    const float* __restrict__ Wx,     // [2][1024][4096]
    const float* __restrict__ bx1,    // bx + GATES
    const float* __restrict__ bh1,    // bh + GATES
    unsigned short* __restrict__ TopsH,  // [2048][1024] bf16 hi, row = s*8+b
    unsigned short* __restrict__ TopsL,  // bf16 lo
    unsigned* __restrict__ hbu,       // packed h [2 layers][2 parity][8][512]
    unsigned* __restrict__ flags)     // [256][16]
{
  extern __shared__ char ldsb[];
  unsigned short* A0 = (unsigned short*)ldsb;
  unsigned short* A1 = A0 + 16384;
  unsigned short* A2 = A1 + 16384;
  unsigned short* hB = A2 + 16384;
  float* Cx = (float*)(ldsb + 131072);
  int tid = threadIdx.x;
  int u0 = blockIdx.x*4;
  const int wv = tid >> 6, ln = tid & 63;
  const int fs0 = tid*16, fs1 = (tid+64)*16, fs2 = (tid+128)*16, fs3 = (tid+192)*16;

  {
    int m = tid >> 4, kseg = tid & 15;
    int col = (m >> 2)*1024 + u0 + (m & 3);
    const float* wsrc[3] = { Wh, Wx + (size_t)HID*GATES, Wh + (size_t)HID*GATES };
    unsigned short* Ad[3] = { A0, A1, A2 };
    for (int tgt=0; tgt<3; ++tgt){
      const float* s = wsrc[tgt] + col;
      #pragma unroll
      for (int run=0; run<8; ++run){
        int k0 = kseg*64 + run*8;
        int kt = k0 >> 5, kg = (k0 >> 3) & 3;
        bf16x8 v;
        #pragma unroll
        for (int e=0;e<8;e++) v[e] = (short)f2bf(s[(size_t)(k0+e)*GATES]);
        *(bf16x8*)&Ad[tgt][kt*512 + ((kg<<4)|m)*8] = v;
      }
    }
  }
  float b1r[4] = {0.f,0.f,0.f,0.f};
  if (tid >= 32 && tid < 64){
    int j = tid & 3;
    #pragma unroll
    for (int g=0;g<4;g++) b1r[g] = bx1[g*1024+u0+j] + bh1[g*1024+u0+j];
  }
  float creg = 0.0f;

  for (int p=0; p<=SEQ; ++p){
    const unsigned* h0b = hbu + (size_t)(p&1)*4096;
    const unsigned* h1b = hbu + 8192 + (size_t)((p+1)&1)*4096;
    float gp0=0.f,gp1=0.f,gp2=0.f,gp3=0.f;
    {
      int colp = tid & 15, seg0 = tid >> 4;
      const unsigned* basep = (colp < 8) ? h0b : h1b;
      const float* srcA = (const float*)(basep + (colp & 7)*512 + seg0*16);
      const float* srcB = srcA + 256;   // seg0+16
      float4 a0,a1,a2,a3,b0,b1,b2,b3;
      // issue-only: MALL stage loads fly while G-prefetch issues below
      asm volatile(
        "global_load_dwordx4 %0, %8, off sc0 sc1\n\t"
        "global_load_dwordx4 %1, %8, off offset:16 sc0 sc1\n\t"
        "global_load_dwordx4 %2, %8, off offset:32 sc0 sc1\n\t"
        "global_load_dwordx4 %3, %8, off offset:48 sc0 sc1\n\t"
        "global_load_dwordx4 %4, %9, off sc0 sc1\n\t"
        "global_load_dwordx4 %5, %9, off offset:16 sc0 sc1\n\t"
        "global_load_dwordx4 %6, %9, off offset:32 sc0 sc1\n\t"
        "global_load_dwordx4 %7, %9, off offset:48 sc0 sc1"
        : "=&v"(a0),"=&v"(a1),"=&v"(a2),"=&v"(a3),
          "=&v"(b0),"=&v"(b1),"=&v"(b2),"=&v"(b3)
        : "v"(srcA), "v"(srcB)
        : "memory");
      // G prefetch overlaps the stage round-trip
      if (tid < 32 && p < SEQ){
        const float* gp = G + ((size_t)p*8 + (tid>>2))*GATES + u0 + (tid&3);
        gp0 = gp[0]; gp1 = gp[1024]; gp2 = gp[2048]; gp3 = gp[3072];
      }
      asm volatile("s_waitcnt vmcnt(0)" ::: "memory");
      __builtin_amdgcn_sched_barrier(0);
      int seg1 = seg0 + 16;
      *(float4*)&hB[seg0*512 + ((0<<4)|colp)*8] = a0;
      *(float4*)&hB[seg0*512 + ((1<<4)|colp)*8] = a1;
      *(float4*)&hB[seg0*512 + ((2<<4)|colp)*8] = a2;
      *(float4*)&hB[seg0*512 + ((3<<4)|colp)*8] = a3;
      *(float4*)&hB[seg1*512 + ((0<<4)|colp)*8] = b0;
      *(float4*)&hB[seg1*512 + ((1<<4)|colp)*8] = b1;
      *(float4*)&hB[seg1*512 + ((2<<4)|colp)*8] = b2;
      *(float4*)&hB[seg1*512 + ((3<<4)|colp)*8] = b3;
    }
    __syncthreads();

    f32x4 C0 = {0.f,0.f,0.f,0.f}, C1 = {0.f,0.f,0.f,0.f}, C2 = {0.f,0.f,0.f,0.f};
    #pragma unroll
    for (int kti=0; kti<8; ++kti){
      int kt = wv + kti*4;
      bf16x8 bB = *(const bf16x8*)&hB[kt*512 + ln*8];
      bf16x8 a0 = *(const bf16x8*)&A0[kt*512 + ln*8];
      bf16x8 a1 = *(const bf16x8*)&A1[kt*512 + ln*8];
      bf16x8 a2 = *(const bf16x8*)&A2[kt*512 + ln*8];
      C0 = __builtin_amdgcn_mfma_f32_16x16x32_bf16(a0, bB, C0, 0,0,0);
      C1 = __builtin_amdgcn_mfma_f32_16x16x32_bf16(a1, bB, C1, 0,0,0);
      C2 = __builtin_amdgcn_mfma_f32_16x16x32_bf16(a2, bB, C2, 0,0,0);
    }
    {
      int cn = ln & 15, mb = (ln >> 4)*4;
      #pragma unroll
      for (int r=0;r<4;r++){
        Cx[((wv*3+0)*16 + mb+r)*17 + cn] = C0[r];
        Cx[((wv*3+1)*16 + mb+r)*17 + cn] = C1[r];
        Cx[((wv*3+2)*16 + mb+r)*17 + cn] = C2[r];
      }
    }
    __syncthreads();

    float hv = 0.f; bool pub = false; unsigned dstbase = 0;
    unsigned short tH = 0, tL = 0; size_t toff = 0; bool do_tops = false;
    if (tid < 32){
      if (p < SEQ){
        int b = tid >> 2, j = tid & 3;
        float gv0=gp0, gv1=gp1, gv2=gp2, gv3=gp3;
        #pragma unroll
        for (int w=0;w<4;w++){
          gv0 += Cx[((w*3+0)*16 + 0*4+j)*17 + b];
          gv1 += Cx[((w*3+0)*16 + 1*4+j)*17 + b];
          gv2 += Cx[((w*3+0)*16 + 2*4+j)*17 + b];
          gv3 += Cx[((w*3+0)*16 + 3*4+j)*17 + b];
        }
        float iv = sigf(gv0), fv = sigf(gv1), ov = sigf(gv3), gg = tanhf_(gv2);
        creg = fv*creg + iv*gg;
        hv = ov * tanhf_(creg);
        pub = true; dstbase = ((unsigned)(p+1)&1u)*4096u;
      }
    } else if (tid < 64){
      if (p > 0){
        int b = (tid-32) >> 2, j = tid & 3;
        float gv0=b1r[0], gv1=b1r[1], gv2=b1r[2], gv3=b1r[3];
        #pragma unroll
        for (int w=0;w<4;w++){
          gv0 += Cx[((w*3+1)*16 + 0*4+j)*17 + b] + Cx[((w*3+2)*16 + 0*4+j)*17 + b+8];
          gv1 += Cx[((w*3+1)*16 + 1*4+j)*17 + b] + Cx[((w*3+2)*16 + 1*4+j)*17 + b+8];
          gv2 += Cx[((w*3+1)*16 + 2*4+j)*17 + b] + Cx[((w*3+2)*16 + 2*4+j)*17 + b+8];
          gv3 += Cx[((w*3+1)*16 + 3*4+j)*17 + b] + Cx[((w*3+2)*16 + 3*4+j)*17 + b+8];
        }
        float iv = sigf(gv0), fv = sigf(gv1), ov = sigf(gv3), gg = tanhf_(gv2);
        creg = fv*creg + iv*gg;
        hv = ov * tanhf_(creg);
        pub = true; dstbase = 8192u + ((unsigned)p&1u)*4096u;
        tH = f2bf(hv);
        tL = f2bf(hv - bf2f(tH));
        toff = ((size_t)(p-1)*8 + b)*HID + u0 + (tid&3);
        do_tops = true;
      }
    }
    if (tid < 64){
      unsigned mybits = (unsigned)f2bf(hv);
      unsigned other  = (unsigned)__shfl_xor((int)mybits, 1);
      if (pub && ((tid & 1) == 0)){
        unsigned word = (mybits & 0xffffu) | (other << 16);
        int b = (tid & 31) >> 2;
        int widx = (u0 >> 1) + ((tid >> 1) & 1);
        (void)__hip_atomic_exchange(&hbu[dstbase + b*512 + widx], word,
                                    __ATOMIC_RELAXED, __HIP_MEMORY_SCOPE_AGENT);
      }
    }

    if (p < SEQ){
      if (tid < 64){
        if (tid == 0){
          asm volatile("s_waitcnt vmcnt(0)" ::: "memory");  // drain hbu exchanges only
          (void)__hip_atomic_exchange(&flags[blockIdx.x*16], (unsigned)(p+1),
                                      __ATOMIC_RELAXED, __HIP_MEMORY_SCOPE_AGENT);
        }
        // Tops store AFTER the flag leaves: off the publish critical path
        if (do_tops){ TopsH[toff] = tH; TopsL[toff] = tL; }
        unsigned tgt = (unsigned)(p+1);
        int spins = 0;
        for (;;){
          unsigned a = __hip_atomic_load(&flags[fs0], __ATOMIC_RELAXED, __HIP_MEMORY_SCOPE_AGENT);
          unsigned b = __hip_atomic_load(&flags[fs1], __ATOMIC_RELAXED, __HIP_MEMORY_SCOPE_AGENT);
          unsigned c = __hip_atomic_load(&flags[fs2], __ATOMIC_RELAXED, __HIP_MEMORY_SCOPE_AGENT);
          unsigned d = __hip_atomic_load(&flags[fs3], __ATOMIC_RELAXED, __HIP_MEMORY_SCOPE_AGENT);
          bool ok = (a >= tgt) && (b >= tgt) && (c >= tgt) && (d >= tgt);
          if (__all(ok)) break;
          __builtin_amdgcn_s_sleep(1);
          if (++spins > 150000){
            for (;;){
              unsigned a2 = __hip_atomic_load(&flags[fs0], __ATOMIC_ACQUIRE, __HIP_MEMORY_SCOPE_AGENT);
              unsigned b2 = __hip_atomic_load(&flags[fs1], __ATOMIC_ACQUIRE, __HIP_MEMORY_SCOPE_AGENT);
              unsigned c2 = __hip_atomic_load(&flags[fs2], __ATOMIC_ACQUIRE, __HIP_MEMORY_SCOPE_AGENT);
              unsigned d2 = __hip_atomic_load(&flags[fs3], __ATOMIC_ACQUIRE, __HIP_MEMORY_SCOPE_AGENT);
              bool ok2 = (a2 >= tgt) && (b2 >= tgt) && (c2 >= tgt) && (d2 >= tgt);
              if (__all(ok2)) break;
              __builtin_amdgcn_s_sleep(8);
              if (++spins > 8000000) break;   // wrong answer beats a hang
            }
            break;
          }
        }
      }
      __syncthreads();
    } else {
      // final phase: no barrier; still emit the last Tops rows
      if (do_tops){ TopsH[toff] = tH; TopsL[toff] = tL; }
    }
  }
}

extern "C" void kernel_launch(void* const* d_in, const int* in_sizes, int n_in,
                              void* d_out, int out_size, void* d_ws, size_t ws_size,
                              hipStream_t stream) {
  const int*   tokens = (const int*)d_in[0];
  const float* emb = (const float*)d_in[1];
  const float* Wx  = (const float*)d_in[2];
  const float* bx  = (const float*)d_in[3];
  const float* Wh  = (const float*)d_in[4];
  const float* bh  = (const float*)d_in[5];
  const float* Wd  = (const float*)d_in[6];
  const float* bd  = (const float*)d_in[7];
  float* out = (float*)d_out;
  float* ws  = (float*)d_ws;

  // ws layout (float offsets):
  //   G 0..8388608 | TopsH 8388608 | TopsL 9437184 | hbu 10485760 |
  //   flags 10502144 | WdH 10506240 .. 26890240 (u16 x 32.768M)
  float* G = ws;
  unsigned short* TopsH = (unsigned short*)(ws + (size_t)8388608);
  unsigned short* TopsL = (unsigned short*)(ws + (size_t)9437184);
  unsigned* hbu   = (unsigned*)(ws + (size_t)10485760);
  unsigned* flags = (unsigned*)(ws + (size_t)10502144);
  unsigned short* WdH = (unsigned short*)(ws + (size_t)10506240);
  const bool wpre = ws_size >= (size_t)26890240*4;

  (void)hipFuncSetAttribute((const void*)k_rec2,
        hipFuncAttributeMaxDynamicSharedMemorySize, 144128);

  // pre-pass: init + Wd conversion + G0 GEMM, one heterogeneous launch
  k_pre<<<dim3(32,15),256,0,stream>>>(Wx, bx, bh, tokens, emb, G,
                                      flags, hbu, Wd, WdH, wpre ? 1 : 0);

  // fused pipelined recurrence: both layers, 257 phases
  k_rec2<<<256,256,144128,stream>>>(G, Wh, Wx, bx + GATES, bh + GATES,
                                    TopsH, TopsL, hbu, flags);

  // final projection
  if (wpre)
    k_proj1<<<dim3(250,8),256,0,stream>>>(TopsH, TopsL, WdH, bd, out);
  else
    k_proj0<<<dim3(250,8),256,0,stream>>>(TopsH, TopsL, Wd, bd, out);
}

// Round 16
// 1757.607 us; speedup vs baseline: 1.0307x; 1.0307x over previous
//
#include <hip/hip_runtime.h>
#include <cstdint>
#include <cstddef>

#define BATCH 8
#define SEQ   256
#define HID   1024
#define GATES 4096   // 4*HID
#define VOC   32000

typedef __attribute__((ext_vector_type(8))) short bf16x8;
typedef __attribute__((ext_vector_type(4))) float f32x4;

// ---------- helpers ----------
__device__ __forceinline__ float sigf(float x){ return 1.0f/(1.0f + __expf(-x)); }
__device__ __forceinline__ float tanhf_(float x){ return 1.0f - 2.0f/(__expf(2.0f*x) + 1.0f); }

__device__ __forceinline__ unsigned short f2bf(float x){
  union { float f; unsigned u; } v; v.f = x;
  unsigned r = v.u + 0x7fffu + ((v.u >> 16) & 1u);
  return (unsigned short)(r >> 16);
}
__device__ __forceinline__ float bf2f(unsigned short h){
  union { float f; unsigned u; } v; v.u = ((unsigned)h) << 16; return v.f;
}

// ---------- k_pre: heterogeneous pre-pass (R15-neutral, kept: fewer launches) ----------
// blocks y<8: G0 = emb[tok]@Wx0 + (bx0+bh0)  (split-bf16 MFMA, R8-validated body)
// blocks y>=8 (224 blocks): init flags/hbu + Wd->bf16 conversion (if wpre)
__global__ __launch_bounds__(256) void k_pre(
    const float* __restrict__ W,     // Wx0 [1024][4096]
    const float* __restrict__ b1,    // bx0
    const float* __restrict__ b2,    // bh0
    const int*   __restrict__ tokens,
    const float* __restrict__ emb,
    float* __restrict__ C,           // G0
    unsigned* __restrict__ flags,
    unsigned* __restrict__ hbu,
    const float* __restrict__ Wd,
    unsigned short* __restrict__ WH,
    int wpre)
{
  __shared__ unsigned short AsH[16*1024], AsL[16*1024];
  __shared__ unsigned short BsH[8*1024],  BsL[8*1024];
  int tid = threadIdx.x;

  if (blockIdx.y >= 8){
    int sid = (blockIdx.y - 8)*32 + blockIdx.x;   // 0..223
    int gtid = sid*256 + tid, nt = 224*256;
    for (int i = gtid; i < 256*16; i += nt) flags[i] = 0u;
    for (int i = gtid; i < 16384; i += nt) hbu[i] = 0u;
    if (wpre){
      const int total4 = (HID*VOC) >> 2;
      for (int i = gtid; i < total4; i += nt){
        float4 v = *(const float4*)(Wd + (size_t)i*4);
        uint2 o;
        o.x = ((unsigned)f2bf(v.x)) | (((unsigned)f2bf(v.y)) << 16);
        o.y = ((unsigned)f2bf(v.z)) | (((unsigned)f2bf(v.w)) << 16);
        *(uint2*)&WH[(size_t)i*4] = o;
      }
    }
    return;
  }

  const int N = GATES;
  int m0 = blockIdx.y*256, n0 = blockIdx.x*128;
  int w = tid >> 6, l = tid & 63;
  int lrow = l & 15, kg = l >> 4;

  f32x4 acc[4][8];
  #pragma unroll
  for (int i=0;i<4;i++){
    #pragma unroll
    for (int j=0;j<8;j++) acc[i][j] = (f32x4){0.f,0.f,0.f,0.f};
  }

  int rA  = tid >> 3, fq = tid & 7;

  const float* arow[8];
  #pragma unroll
  for (int i=0;i<8;i++){
    int gm = m0 + rA + 32*i;
    arow[i] = emb + (size_t)tokens[(gm&7)*SEQ + (gm>>3)]*1024;
  }

  for (int kt=0; kt<32; ++kt){
    int k0 = kt*32;
    float4 av[8];
    #pragma unroll
    for (int i=0;i<8;i++)
      av[i] = *(const float4*)(arow[i] + k0 + fq*4);
    float4 wv[4];
    #pragma unroll
    for (int i=0;i<4;i++)
      wv[i] = *(const float4*)(W + (size_t)(k0 + rA)*N + n0 + fq*4 + 32*i);
    __syncthreads();
    #pragma unroll
    for (int i=0;i<8;i++){
      int r = rA + 32*i;
      int base = (r >> 4)*1024 + ((fq >> 1)*16 + (r & 15))*8 + (fq & 1)*4;
      float xs[4] = {av[i].x, av[i].y, av[i].z, av[i].w};
      unsigned long long ph = 0ull, pl = 0ull;
      #pragma unroll
      for (int c=0;c<4;c++){
        unsigned short h = f2bf(xs[c]);
        unsigned short lo = f2bf(xs[c] - bf2f(h));
        ph |= ((unsigned long long)h) << (16*c);
        pl |= ((unsigned long long)lo) << (16*c);
      }
      *(unsigned long long*)&AsH[base] = ph;
      *(unsigned long long*)&AsL[base] = pl;
    }
    #pragma unroll
    for (int i=0;i<4;i++){
      float xs[4] = {wv[i].x, wv[i].y, wv[i].z, wv[i].w};
      #pragma unroll
      for (int c=0;c<4;c++){
        int col = fq*4 + 32*i + c;
        int idx = (col >> 4)*1024 + ((rA >> 3)*16 + (col & 15))*8 + (rA & 7);
        unsigned short h = f2bf(xs[c]);
        BsH[idx] = h;
        BsL[idx] = f2bf(xs[c] - bf2f(h));
      }
    }
    __syncthreads();
    bf16x8 ah[4], al[4];
    #pragma unroll
    for (int i=0;i<4;i++){
      int fi = w*4 + i;
      ah[i] = *(const bf16x8*)&AsH[fi*1024 + l*8];
      al[i] = *(const bf16x8*)&AsL[fi*1024 + l*8];
    }
    #pragma unroll
    for (int jh=0;jh<2;jh++){
      bf16x8 bh_[4], bl_[4];
      #pragma unroll
      for (int j=0;j<4;j++){
        bh_[j] = *(const bf16x8*)&BsH[(jh*4+j)*1024 + l*8];
        bl_[j] = *(const bf16x8*)&BsL[(jh*4+j)*1024 + l*8];
      }
      #pragma unroll
      for (int i=0;i<4;i++){
        #pragma unroll
        for (int j=0;j<4;j++){
          f32x4 a = acc[i][jh*4+j];
          a = __builtin_amdgcn_mfma_f32_16x16x32_bf16(ah[i], bh_[j], a, 0,0,0);
          a = __builtin_amdgcn_mfma_f32_16x16x32_bf16(ah[i], bl_[j], a, 0,0,0);
          a = __builtin_amdgcn_mfma_f32_16x16x32_bf16(al[i], bh_[j], a, 0,0,0);
          acc[i][jh*4+j] = a;
        }
      }
    }
    __syncthreads();
  }

  int mbase = m0 + w*64 + kg*4;
  #pragma unroll
  for (int jj=0;jj<8;jj++){
    int gn = n0 + jj*16 + lrow;
    float bias = b1[gn] + b2[gn];
    #pragma unroll
    for (int i=0;i<4;i++){
      #pragma unroll
      for (int r=0;r<4;r++){
        int m = mbase + i*16 + r;
        C[(size_t)m*N + gn] = acc[i][jj][r] + bias;
      }
    }
  }
}

// ---------- k_proj1: 2-pass projection, single-bf16 W, 80KB LDS, prefetch (R14-proven) ----------
__global__ __launch_bounds__(256,2) void k_proj1(
    const unsigned short* __restrict__ AH,
    const unsigned short* __restrict__ AL,
    const unsigned short* __restrict__ WH,
    const float* __restrict__ bd,
    float* __restrict__ C)
{
  __shared__ unsigned short AsH[16*1024], AsL[16*1024];
  __shared__ unsigned short BsH[8*1024];
  int tid = threadIdx.x;
  int m0 = blockIdx.y*256, n0 = blockIdx.x*128;
  int w = tid >> 6, l = tid & 63;
  int lrow = l & 15, kg = l >> 4;

  f32x4 acc[4][8];
  #pragma unroll
  for (int i=0;i<4;i++){
    #pragma unroll
    for (int j=0;j<8;j++) acc[i][j] = (f32x4){0.f,0.f,0.f,0.f};
  }

  int rA = tid >> 3, fq = tid & 7;

  uint2 avh[8], avl[8], wvh[4];
  #pragma unroll
  for (int i=0;i<8;i++){
    size_t off = (size_t)(m0 + rA + 32*i)*1024 + fq*4;
    avh[i] = *(const uint2*)&AH[off];
    avl[i] = *(const uint2*)&AL[off];
  }
  #pragma unroll
  for (int i=0;i<4;i++)
    wvh[i] = *(const uint2*)&WH[(size_t)rA*VOC + n0 + fq*4 + 32*i];

  for (int kt=0; kt<32; ++kt){
    __syncthreads();
    #pragma unroll
    for (int i=0;i<8;i++){
      int r = rA + 32*i;
      int base = (r >> 4)*1024 + ((fq >> 1)*16 + (r & 15))*8 + (fq & 1)*4;
      *(uint2*)&AsH[base] = avh[i];
      *(uint2*)&AsL[base] = avl[i];
    }
    #pragma unroll
    for (int i=0;i<4;i++){
      #pragma unroll
      for (int c=0;c<4;c++){
        int col = fq*4 + 32*i + c;
        int idx = (col >> 4)*1024 + ((rA >> 3)*16 + (col & 15))*8 + (rA & 7);
        BsH[idx] = ((const unsigned short*)&wvh[i])[c];
      }
    }
    __syncthreads();
    if (kt < 31){
      int k0 = (kt+1)*32;
      #pragma unroll
      for (int i=0;i<8;i++){
        size_t off = (size_t)(m0 + rA + 32*i)*1024 + k0 + fq*4;
        avh[i] = *(const uint2*)&AH[off];
        avl[i] = *(const uint2*)&AL[off];
      }
      #pragma unroll
      for (int i=0;i<4;i++)
        wvh[i] = *(const uint2*)&WH[(size_t)(k0 + rA)*VOC + n0 + fq*4 + 32*i];
    }
    bf16x8 ah[4], al[4];
    #pragma unroll
    for (int i=0;i<4;i++){
      int fi = w*4 + i;
      ah[i] = *(const bf16x8*)&AsH[fi*1024 + l*8];
      al[i] = *(const bf16x8*)&AsL[fi*1024 + l*8];
    }
    #pragma unroll
    for (int jh=0;jh<2;jh++){
      bf16x8 bh_[4];
      #pragma unroll
      for (int j=0;j<4;j++)
        bh_[j] = *(const bf16x8*)&BsH[(jh*4+j)*1024 + l*8];
      #pragma unroll
      for (int i=0;i<4;i++){
        #pragma unroll
        for (int j=0;j<4;j++){
          f32x4 a = acc[i][jh*4+j];
          a = __builtin_amdgcn_mfma_f32_16x16x32_bf16(ah[i], bh_[j], a, 0,0,0);
          a = __builtin_amdgcn_mfma_f32_16x16x32_bf16(al[i], bh_[j], a, 0,0,0);
          acc[i][jh*4+j] = a;
        }
      }
    }
  }
  __syncthreads();

  int mbase = m0 + w*64 + kg*4;
  #pragma unroll
  for (int jj=0;jj<8;jj++){
    int gn = n0 + jj*16 + lrow;
    float bias = bd[gn];
    #pragma unroll
    for (int i=0;i<4;i++){
      #pragma unroll
      for (int r=0;r<4;r++){
        int m = mbase + i*16 + r;
        size_t crow = (size_t)((m & 7)*SEQ + (m >> 3));
        C[crow*(size_t)VOC + gn] = acc[i][jj][r] + bias;
      }
    }
  }
}

// ---------- k_proj0: fallback (f32 W, 3-pass, R13-proven) ----------
__global__ __launch_bounds__(256) void k_proj0(
    const unsigned short* __restrict__ AH,
    const unsigned short* __restrict__ AL,
    const float* __restrict__ Wf,
    const float* __restrict__ bd,
    float* __restrict__ C)
{
  __shared__ unsigned short AsH[16*1024], AsL[16*1024];
  __shared__ unsigned short BsH[8*1024],  BsL[8*1024];
  int tid = threadIdx.x;
  int m0 = blockIdx.y*256, n0 = blockIdx.x*128;
  int w = tid >> 6, l = tid & 63;
  int lrow = l & 15, kg = l >> 4;

  f32x4 acc[4][8];
  #pragma unroll
  for (int i=0;i<4;i++){
    #pragma unroll
    for (int j=0;j<8;j++) acc[i][j] = (f32x4){0.f,0.f,0.f,0.f};
  }

  int rA = tid >> 3, fq = tid & 7;

  for (int kt=0; kt<32; ++kt){
    int k0 = kt*32;
    uint2 avh[8], avl[8];
    #pragma unroll
    for (int i=0;i<8;i++){
      size_t off = (size_t)(m0 + rA + 32*i)*1024 + k0 + fq*4;
      avh[i] = *(const uint2*)&AH[off];
      avl[i] = *(const uint2*)&AL[off];
    }
    float4 wvf[4];
    #pragma unroll
    for (int i=0;i<4;i++)
      wvf[i] = *(const float4*)(Wf + (size_t)(k0 + rA)*VOC + n0 + fq*4 + 32*i);
    __syncthreads();
    #pragma unroll
    for (int i=0;i<8;i++){
      int r = rA + 32*i;
      int base = (r >> 4)*1024 + ((fq >> 1)*16 + (r & 15))*8 + (fq & 1)*4;
      *(uint2*)&AsH[base] = avh[i];
      *(uint2*)&AsL[base] = avl[i];
    }
    #pragma unroll
    for (int i=0;i<4;i++){
      float xs[4] = {wvf[i].x, wvf[i].y, wvf[i].z, wvf[i].w};
      #pragma unroll
      for (int c=0;c<4;c++){
        int col = fq*4 + 32*i + c;
        int idx = (col >> 4)*1024 + ((rA >> 3)*16 + (col & 15))*8 + (rA & 7);
        unsigned short h = f2bf(xs[c]);
        BsH[idx] = h;
        BsL[idx] = f2bf(xs[c] - bf2f(h));
      }
    }
    __syncthreads();
    bf16x8 ah[4], al[4];
    #pragma unroll
    for (int i=0;i<4;i++){
      int fi = w*4 + i;
      ah[i] = *(const bf16x8*)&AsH[fi*1024 + l*8];
      al[i] = *(const bf16x8*)&AsL[fi*1024 + l*8];
    }
    #pragma unroll
    for (int jh=0;jh<2;jh++){
      bf16x8 bh_[4], bl_[4];
      #pragma unroll
      for (int j=0;j<4;j++){
        bh_[j] = *(const bf16x8*)&BsH[(jh*4+j)*1024 + l*8];
        bl_[j] = *(const bf16x8*)&BsL[(jh*4+j)*1024 + l*8];
      }
      #pragma unroll
      for (int i=0;i<4;i++){
        #pragma unroll
        for (int j=0;j<4;j++){
          f32x4 a = acc[i][jh*4+j];
          a = __builtin_amdgcn_mfma_f32_16x16x32_bf16(ah[i], bh_[j], a, 0,0,0);
          a = __builtin_amdgcn_mfma_f32_16x16x32_bf16(ah[i], bl_[j], a, 0,0,0);
          a = __builtin_amdgcn_mfma_f32_16x16x32_bf16(al[i], bh_[j], a, 0,0,0);
          acc[i][jh*4+j] = a;
        }
      }
    }
    __syncthreads();
  }

  int mbase = m0 + w*64 + kg*4;
  #pragma unroll
  for (int jj=0;jj<8;jj++){
    int gn = n0 + jj*16 + lrow;
    float bias = bd[gn];
    #pragma unroll
    for (int i=0;i<4;i++){
      #pragma unroll
      for (int r=0;r<4;r++){
        int m = mbase + i*16 + r;
        size_t crow = (size_t)((m & 7)*SEQ + (m >> 3));
        C[crow*(size_t)VOC + gn] = acc[i][jj][r] + bias;
      }
    }
  }
}

// ---------- fused 2-layer pipelined recurrence (R12/R14-proven body, verbatim revert) ----------
__global__ __launch_bounds__(256) void k_rec2(
    const float* __restrict__ G,      // G0 [2048][4096], bias folded
    const float* __restrict__ Wh,     // [2][1024][4096]
    const float* __restrict__ Wx,     // [2][1024][4096]
    const float* __restrict__ bx1,    // bx + GATES
    const float* __restrict__ bh1,    // bh + GATES
    unsigned short* __restrict__ TopsH,  // [2048][1024] bf16 hi, row = s*8+b
    unsigned short* __restrict__ TopsL,  // bf16 lo
    unsigned* __restrict__ hbu,       // packed h [2 layers][2 parity][8][512]
    unsigned* __restrict__ flags)     // [256][16]
{
  extern __shared__ char ldsb[];
  unsigned short* A0 = (unsigned short*)ldsb;
  unsigned short* A1 = A0 + 16384;
  unsigned short* A2 = A1 + 16384;
  unsigned short* hB = A2 + 16384;
  float* Cx = (float*)(ldsb + 131072);
  int tid = threadIdx.x;
  int u0 = blockIdx.x*4;
  const int wv = tid >> 6, ln = tid & 63;
  const int fs0 = tid*16, fs1 = (tid+64)*16, fs2 = (tid+128)*16, fs3 = (tid+192)*16;

  {
    int m = tid >> 4, kseg = tid & 15;
    int col = (m >> 2)*1024 + u0 + (m & 3);
    const float* wsrc[3] = { Wh, Wx + (size_t)HID*GATES, Wh + (size_t)HID*GATES };
    unsigned short* Ad[3] = { A0, A1, A2 };
    for (int tgt=0; tgt<3; ++tgt){
      const float* s = wsrc[tgt] + col;
      #pragma unroll
      for (int run=0; run<8; ++run){
        int k0 = kseg*64 + run*8;
        int kt = k0 >> 5, kg = (k0 >> 3) & 3;
        bf16x8 v;
        #pragma unroll
        for (int e=0;e<8;e++) v[e] = (short)f2bf(s[(size_t)(k0+e)*GATES]);
        *(bf16x8*)&Ad[tgt][kt*512 + ((kg<<4)|m)*8] = v;
      }
    }
  }
  float b1r[4] = {0.f,0.f,0.f,0.f};
  if (tid >= 32 && tid < 64){
    int j = tid & 3;
    #pragma unroll
    for (int g=0;g<4;g++) b1r[g] = bx1[g*1024+u0+j] + bh1[g*1024+u0+j];
  }
  float creg = 0.0f;

  for (int p=0; p<=SEQ; ++p){
    const unsigned* h0b = hbu + (size_t)(p&1)*4096;
    const unsigned* h1b = hbu + 8192 + (size_t)((p+1)&1)*4096;
    {
      int colp = tid & 15, seg0 = tid >> 4;
      #pragma unroll
      for (int i=0;i<2;i++){
        int seg = seg0 + 16*i;
        const float* src = (const float*)(((colp < 8) ? h0b : h1b)
                                          + (colp & 7)*512 + seg*16);
        float4 r0,r1,r2,r3;
        asm volatile(
          "global_load_dwordx4 %0, %4, off sc0 sc1\n\t"
          "global_load_dwordx4 %1, %4, off offset:16 sc0 sc1\n\t"
          "global_load_dwordx4 %2, %4, off offset:32 sc0 sc1\n\t"
          "global_load_dwordx4 %3, %4, off offset:48 sc0 sc1\n\t"
          "s_waitcnt vmcnt(0)"
          : "=&v"(r0),"=&v"(r1),"=&v"(r2),"=&v"(r3)
          : "v"(src)
          : "memory");
        *(float4*)&hB[seg*512 + ((0<<4)|colp)*8] = r0;
        *(float4*)&hB[seg*512 + ((1<<4)|colp)*8] = r1;
        *(float4*)&hB[seg*512 + ((2<<4)|colp)*8] = r2;
        *(float4*)&hB[seg*512 + ((3<<4)|colp)*8] = r3;
      }
    }
    float gp0=0.f,gp1=0.f,gp2=0.f,gp3=0.f;
    if (tid < 32 && p < SEQ){
      const float* gp = G + ((size_t)p*8 + (tid>>2))*GATES + u0 + (tid&3);
      gp0 = gp[0]; gp1 = gp[1024]; gp2 = gp[2048]; gp3 = gp[3072];
    }
    __syncthreads();

    f32x4 C0 = {0.f,0.f,0.f,0.f}, C1 = {0.f,0.f,0.f,0.f}, C2 = {0.f,0.f,0.f,0.f};
    #pragma unroll
    for (int kti=0; kti<8; ++kti){
      int kt = wv + kti*4;
      bf16x8 bB = *(const bf16x8*)&hB[kt*512 + ln*8];
      bf16x8 a0 = *(const bf16x8*)&A0[kt*512 + ln*8];
      bf16x8 a1 = *(const bf16x8*)&A1[kt*512 + ln*8];
      bf16x8 a2 = *(const bf16x8*)&A2[kt*512 + ln*8];
      C0 = __builtin_amdgcn_mfma_f32_16x16x32_bf16(a0, bB, C0, 0,0,0);
      C1 = __builtin_amdgcn_mfma_f32_16x16x32_bf16(a1, bB, C1, 0,0,0);
      C2 = __builtin_amdgcn_mfma_f32_16x16x32_bf16(a2, bB, C2, 0,0,0);
    }
    {
      int cn = ln & 15, mb = (ln >> 4)*4;
      #pragma unroll
      for (int r=0;r<4;r++){
        Cx[((wv*3+0)*16 + mb+r)*17 + cn] = C0[r];
        Cx[((wv*3+1)*16 + mb+r)*17 + cn] = C1[r];
        Cx[((wv*3+2)*16 + mb+r)*17 + cn] = C2[r];
      }
    }
    __syncthreads();

    float hv = 0.f; bool pub = false; unsigned dstbase = 0;
    if (tid < 32){
      if (p < SEQ){
        int b = tid >> 2, j = tid & 3;
        float gv0=gp0, gv1=gp1, gv2=gp2, gv3=gp3;
        #pragma unroll
        for (int w=0;w<4;w++){
          gv0 += Cx[((w*3+0)*16 + 0*4+j)*17 + b];
          gv1 += Cx[((w*3+0)*16 + 1*4+j)*17 + b];
          gv2 += Cx[((w*3+0)*16 + 2*4+j)*17 + b];
          gv3 += Cx[((w*3+0)*16 + 3*4+j)*17 + b];
        }
        float iv = sigf(gv0), fv = sigf(gv1), ov = sigf(gv3), gg = tanhf_(gv2);
        creg = fv*creg + iv*gg;
        hv = ov * tanhf_(creg);
        pub = true; dstbase = ((unsigned)(p+1)&1u)*4096u;
      }
    } else if (tid < 64){
      if (p > 0){
        int b = (tid-32) >> 2, j = tid & 3;
        float gv0=b1r[0], gv1=b1r[1], gv2=b1r[2], gv3=b1r[3];
        #pragma unroll
        for (int w=0;w<4;w++){
          gv0 += Cx[((w*3+1)*16 + 0*4+j)*17 + b] + Cx[((w*3+2)*16 + 0*4+j)*17 + b+8];
          gv1 += Cx[((w*3+1)*16 + 1*4+j)*17 + b] + Cx[((w*3+2)*16 + 1*4+j)*17 + b+8];
          gv2 += Cx[((w*3+1)*16 + 2*4+j)*17 + b] + Cx[((w*3+2)*16 + 2*4+j)*17 + b+8];
          gv3 += Cx[((w*3+1)*16 + 3*4+j)*17 + b] + Cx[((w*3+2)*16 + 3*4+j)*17 + b+8];
        }
        float iv = sigf(gv0), fv = sigf(gv1), ov = sigf(gv3), gg = tanhf_(gv2);
        creg = fv*creg + iv*gg;
        hv = ov * tanhf_(creg);
        pub = true; dstbase = 8192u + ((unsigned)p&1u)*4096u;
        unsigned short hi = f2bf(hv);
        unsigned short lo = f2bf(hv - bf2f(hi));
        size_t off = ((size_t)(p-1)*8 + b)*HID + u0 + (tid&3);
        TopsH[off] = hi;
        TopsL[off] = lo;
      }
    }
    if (tid < 64){
      unsigned mybits = (unsigned)f2bf(hv);
      unsigned other  = (unsigned)__shfl_xor((int)mybits, 1);
      if (pub && ((tid & 1) == 0)){
        unsigned word = (mybits & 0xffffu) | (other << 16);
        int b = (tid & 31) >> 2;
        int widx = (u0 >> 1) + ((tid >> 1) & 1);
        (void)__hip_atomic_exchange(&hbu[dstbase + b*512 + widx], word,
                                    __ATOMIC_RELAXED, __HIP_MEMORY_SCOPE_AGENT);
      }
    }

    if (p < SEQ){
      if (tid < 64){
        if (tid == 0){
          asm volatile("s_waitcnt vmcnt(0)" ::: "memory");
          (void)__hip_atomic_exchange(&flags[blockIdx.x*16], (unsigned)(p+1),
                                      __ATOMIC_RELAXED, __HIP_MEMORY_SCOPE_AGENT);
        }
        unsigned tgt = (unsigned)(p+1);
        int spins = 0;
        for (;;){
          unsigned a = __hip_atomic_load(&flags[fs0], __ATOMIC_RELAXED, __HIP_MEMORY_SCOPE_AGENT);
          unsigned b = __hip_atomic_load(&flags[fs1], __ATOMIC_RELAXED, __HIP_MEMORY_SCOPE_AGENT);
          unsigned c = __hip_atomic_load(&flags[fs2], __ATOMIC_RELAXED, __HIP_MEMORY_SCOPE_AGENT);
          unsigned d = __hip_atomic_load(&flags[fs3], __ATOMIC_RELAXED, __HIP_MEMORY_SCOPE_AGENT);
          bool ok = (a >= tgt) && (b >= tgt) && (c >= tgt) && (d >= tgt);
          if (__all(ok)) break;
          __builtin_amdgcn_s_sleep(1);
          if (++spins > 150000){
            for (;;){
              unsigned a2 = __hip_atomic_load(&flags[fs0], __ATOMIC_ACQUIRE, __HIP_MEMORY_SCOPE_AGENT);
              unsigned b2 = __hip_atomic_load(&flags[fs1], __ATOMIC_ACQUIRE, __HIP_MEMORY_SCOPE_AGENT);
              unsigned c2 = __hip_atomic_load(&flags[fs2], __ATOMIC_ACQUIRE, __HIP_MEMORY_SCOPE_AGENT);
              unsigned d2 = __hip_atomic_load(&flags[fs3], __ATOMIC_ACQUIRE, __HIP_MEMORY_SCOPE_AGENT);
              bool ok2 = (a2 >= tgt) && (b2 >= tgt) && (c2 >= tgt) && (d2 >= tgt);
              if (__all(ok2)) break;
              __builtin_amdgcn_s_sleep(8);
              if (++spins > 8000000) break;   // wrong answer beats a hang
            }
            break;
          }
        }
      }
      __syncthreads();
    }
  }
}

extern "C" void kernel_launch(void* const* d_in, const int* in_sizes, int n_in,
                              void* d_out, int out_size, void* d_ws, size_t ws_size,
                              hipStream_t stream) {
  const int*   tokens = (const int*)d_in[0];
  const float* emb = (const float*)d_in[1];
  const float* Wx  = (const float*)d_in[2];
  const float* bx  = (const float*)d_in[3];
  const float* Wh  = (const float*)d_in[4];
  const float* bh  = (const float*)d_in[5];
  const float* Wd  = (const float*)d_in[6];
  const float* bd  = (const float*)d_in[7];
  float* out = (float*)d_out;
  float* ws  = (float*)d_ws;

  // ws layout (float offsets):
  //   G 0..8388608 | TopsH 8388608 | TopsL 9437184 | hbu 10485760 |
  //   flags 10502144 | WdH 10506240 .. 26890240 (u16 x 32.768M)
  float* G = ws;
  unsigned short* TopsH = (unsigned short*)(ws + (size_t)8388608);
  unsigned short* TopsL = (unsigned short*)(ws + (size_t)9437184);
  unsigned* hbu   = (unsigned*)(ws + (size_t)10485760);
  unsigned* flags = (unsigned*)(ws + (size_t)10502144);
  unsigned short* WdH = (unsigned short*)(ws + (size_t)10506240);
  const bool wpre = ws_size >= (size_t)26890240*4;

  (void)hipFuncSetAttribute((const void*)k_rec2,
        hipFuncAttributeMaxDynamicSharedMemorySize, 144128);

  // pre-pass: init + Wd conversion + G0 GEMM, one heterogeneous launch
  k_pre<<<dim3(32,15),256,0,stream>>>(Wx, bx, bh, tokens, emb, G,
                                      flags, hbu, Wd, WdH, wpre ? 1 : 0);

  // fused pipelined recurrence: both layers, 257 phases
  k_rec2<<<256,256,144128,stream>>>(G, Wh, Wx, bx + GATES, bh + GATES,
                                    TopsH, TopsL, hbu, flags);

  // final projection
  if (wpre)
    k_proj1<<<dim3(250,8),256,0,stream>>>(TopsH, TopsL, WdH, bd, out);
  else
    k_proj0<<<dim3(250,8),256,0,stream>>>(TopsH, TopsL, Wd, bd, out);
}